// Round 7
// baseline (359.433 us; speedup 1.0000x reference)
//
#include <hip/hip_runtime.h>
#include <stdint.h>

typedef unsigned short u16;
typedef uint8_t u8;
typedef __bf16 bf16x8 __attribute__((ext_vector_type(8)));
typedef float f32x4 __attribute__((ext_vector_type(4)));
typedef int i32x8 __attribute__((ext_vector_type(8)));

#define D_MODEL 1024
#define NHEADS  16
#define DHEAD   64
#define BATCH   8
#define SEQ     1024
#define MTOT    (BATCH*SEQ)          // 8192 rows

#define GPTR(p) ((const __attribute__((address_space(1))) void*)(p))
#define LPTR(p) ((__attribute__((address_space(3))) void*)(p))

// Device-only builtins (host pass just needs to parse — r2 lesson)
#if defined(__HIP_DEVICE_COMPILE__)
  #define MFMA_FP8_16x16x128(a, b, c) \
      __builtin_amdgcn_mfma_scale_f32_16x16x128_f8f6f4((a), (b), (c), 0, 0, 0, 127, 0, 127)
  #define CVT_PK_FP8(a, b, old, w) __builtin_amdgcn_cvt_pk_fp8_f32((a), (b), (old), (w))
#else
  #define MFMA_FP8_16x16x128(a, b, c) (c)
  #define CVT_PK_FP8(a, b, old, w) (0)
#endif

__device__ __forceinline__ u16 f2bf(float f) {
    union { float f; uint32_t u; } v; v.f = f;
    uint32_t u = v.u;
    u += 0x7fffu + ((u >> 16) & 1u);  // RNE
    return (u16)(u >> 16);
}

// pack low16 of two ints: result = [i1.low16 : i0.low16]
__device__ __forceinline__ uint32_t pklo(int i1, int i0) {
    return __builtin_amdgcn_perm((uint32_t)i1, (uint32_t)i0, 0x05040100u);
}

// --------------- merged prep: LayerNorm->fp8 (blocks 0..8191) and
//                 weight transpose->fp8 (blocks 8192..12287)
__global__ __launch_bounds__(256) void prep_inputs(
    const float* __restrict__ z, const float* __restrict__ w,
    const float* __restrict__ b, uint32_t* __restrict__ znf,
    const float* __restrict__ Wqkv, const float* __restrict__ Wproj,
    u8* __restrict__ outQkv, u8* __restrict__ outProj)
{
    __shared__ float red[8];
    __shared__ u8 tile[32][36];
    const int bid = blockIdx.x;
    const int t = threadIdx.x;
    if (bid < MTOT) {
        // ---- LayerNorm row
        const int row = bid;
        const float4 v = reinterpret_cast<const float4*>(z + (size_t)row * D_MODEL)[t];
        float s  = v.x + v.y + v.z + v.w;
        float s2 = v.x*v.x + v.y*v.y + v.z*v.z + v.w*v.w;
        #pragma unroll
        for (int off = 32; off; off >>= 1) {
            s  += __shfl_down(s,  off, 64);
            s2 += __shfl_down(s2, off, 64);
        }
        const int wave = t >> 6, lane = t & 63;
        if (lane == 0) { red[wave] = s; red[wave + 4] = s2; }
        __syncthreads();
        if (t == 0) {
            float ts  = red[0] + red[1] + red[2] + red[3];
            float ts2 = red[4] + red[5] + red[6] + red[7];
            float mu  = ts * (1.0f / D_MODEL);
            float var = ts2 * (1.0f / D_MODEL) - mu * mu;
            red[0] = mu; red[1] = rsqrtf(var + 1e-5f);
        }
        __syncthreads();
        const float mu = red[0], rstd = red[1];
        const float4 wv = reinterpret_cast<const float4*>(w)[t];
        const float4 bv = reinterpret_cast<const float4*>(b)[t];
        const float x0 = (v.x - mu) * rstd * wv.x + bv.x;
        const float x1 = (v.y - mu) * rstd * wv.y + bv.y;
        const float x2 = (v.z - mu) * rstd * wv.z + bv.z;
        const float x3 = (v.w - mu) * rstd * wv.w + bv.w;
        int pk = CVT_PK_FP8(x0, x1, 0, false);
        pk = CVT_PK_FP8(x2, x3, pk, true);
        znf[(size_t)row * (D_MODEL / 4) + t] = (uint32_t)pk;
    } else {
        // ---- weight transpose + fp8 cast (32x32 tile)
        const int bx = bid - MTOT;            // 0..4095
        const int cx = bx & 127;              // 128 column-tiles
        const int r0 = (bx >> 7) * 32;        // 32 row-tiles
        const float* in; u8* out; int C;
        if (cx < 96) { in = Wqkv;  out = outQkv;  C = 3072; }
        else         { in = Wproj; out = outProj; C = 1024; }
        const int c0 = (cx < 96 ? cx : cx - 96) * 32;
        const int tx = t & 31, ty = t >> 5;   // 32x8
        #pragma unroll
        for (int i = 0; i < 4; ++i) {
            const float f = in[(size_t)(r0 + ty + i*8) * C + c0 + tx];
            tile[ty + i*8][tx] = (u8)(CVT_PK_FP8(f, 0.f, 0, false) & 0xFF);
        }
        __syncthreads();
        #pragma unroll
        for (int i = 0; i < 4; ++i)
            out[(size_t)(c0 + ty + i*8) * D_MODEL + r0 + tx] = tile[tx][ty + i*8];
    }
}

// q scale: 0.125 * log2(e) * 128 — the x128 of the Schraudolph exp2 is folded
// into the q values themselves; the +16250 offset is folded into the QK MFMA
// C-operand (SMINIT in attn_kernel). So the per-score softmax work is a single
// magic-add (v_add_f32) + perm pack.
#define QSCALE 23.0831207f

// ---------------------------------------------------------- fp8 GEMM mainloop
// r10 single-buffer form (proven): 128x128 tile, K-tile=128B, 4 waves;
// XOR swizzle; global_load_lds width-16. (2-phase dbuf tested r4: neutral,
// matches the m99/m100 known-null; costs LDS.)
#define GEMM_PRELUDE                                                            \
    const int tid = threadIdx.x;                                                \
    const int wave = tid >> 6, lane = tid & 63;                                 \
    const int lm = lane & 15, g = lane >> 4;                                    \
    const int wm = (wave >> 1) * 64, wn = (wave & 1) * 64;                      \
    const int srow = tid >> 3;                                                  \
    const int sseg = tid & 7;                                                   \
    const int sgcol = (sseg ^ (srow & 7)) * 16;                                 \
    const int xl = lm & 7;                                                      \
    const int ca0 = ((2 * g) ^ xl) * 16;                                        \
    const int ca1 = ((2 * g + 1) ^ xl) * 16;

#define FP8_KLOOP(As_, Bs_, A_, Bt_, n0_, MFMA_STMT)                            \
    f32x4 acc[4][4] = {};                                                       \
    for (int k0 = 0; k0 < D_MODEL; k0 += 128) {                                 \
        _Pragma("unroll")                                                       \
        for (int c = 0; c < 4; ++c) {                                           \
            const int r = srow + c * 32;                                        \
            __builtin_amdgcn_global_load_lds(                                   \
                GPTR(&A_[(size_t)(m0 + r) * D_MODEL + k0 + sgcol]),             \
                LPTR(&As_[r * 128 + sseg * 16]), 16, 0, 0);                     \
            __builtin_amdgcn_global_load_lds(                                   \
                GPTR(&Bt_[(size_t)((n0_) + r) * D_MODEL + k0 + sgcol]),         \
                LPTR(&Bs_[r * 128 + sseg * 16]), 16, 0, 0);                     \
        }                                                                       \
        __syncthreads();                                                        \
        i32x8 af[4], bfr[4];                                                    \
        _Pragma("unroll")                                                       \
        for (int i = 0; i < 4; ++i) {                                           \
            const uint4 alo = *reinterpret_cast<const uint4*>(&As_[(wm + i*16 + lm) * 128 + ca0]); \
            const uint4 ahi = *reinterpret_cast<const uint4*>(&As_[(wm + i*16 + lm) * 128 + ca1]); \
            af[i][0] = alo.x; af[i][1] = alo.y; af[i][2] = alo.z; af[i][3] = alo.w; \
            af[i][4] = ahi.x; af[i][5] = ahi.y; af[i][6] = ahi.z; af[i][7] = ahi.w; \
            const uint4 blo = *reinterpret_cast<const uint4*>(&Bs_[(wn + i*16 + lm) * 128 + ca0]); \
            const uint4 bhi = *reinterpret_cast<const uint4*>(&Bs_[(wn + i*16 + lm) * 128 + ca1]); \
            bfr[i][0] = blo.x; bfr[i][1] = blo.y; bfr[i][2] = blo.z; bfr[i][3] = blo.w; \
            bfr[i][4] = bhi.x; bfr[i][5] = bhi.y; bfr[i][6] = bhi.z; bfr[i][7] = bhi.w; \
        }                                                                       \
        _Pragma("unroll")                                                       \
        for (int i = 0; i < 4; ++i)                                             \
            _Pragma("unroll")                                                   \
            for (int j = 0; j < 4; ++j)                                         \
                MFMA_STMT;                                                      \
        __syncthreads();                                                        \
    }

// -------------------------------------------- merged QKV GEMM (r13/r14)
// grid x: 0..15 = q/k columns (swapped-operand MFMA, lane owns 4 dh);
//         16..23 = v columns (unswapped, writes vT[b,h,dh,t] direct).
// r14: T1 XCD-aware bijective swizzle — each XCD gets 192 consecutive tiles
// (8 A-panels x full B sweep ~= 4MB = its L2). nwg=1536 %8==0 -> valid.
__global__ __launch_bounds__(256, 2) void gemm_qkv(
    const u8* __restrict__ A, const u8* __restrict__ Bt,
    const float* __restrict__ bias,
    u16* __restrict__ q, u16* __restrict__ k, u16* __restrict__ vT)
{
    __shared__ u8 As[128 * 128];
    __shared__ u8 Bs[128 * 128];
    GEMM_PRELUDE
    const int lin = blockIdx.y * 24 + blockIdx.x;   // HW dispatch order (x fastest)
    const int nl  = (lin & 7) * 192 + (lin >> 3);   // XCD-contiguous remap
    const int bx  = nl % 24;
    const int m0  = (nl / 24) * 128;
    if (bx < 16) {
        const int n0 = bx * 128;
        FP8_KLOOP(As, Bs, A, Bt, n0, acc[i][j] = MFMA_FP8_16x16x128(bfr[j], af[i], acc[i][j]))
        const int colbase = n0 + wn;
        const int sel = colbase >> 10;          // 0=q 1=k
        const int h = (colbase & 1023) >> 6;
        u16* dst = (sel == 0) ? q : k;
        const float scl = (sel == 0) ? QSCALE : 1.0f;
        #pragma unroll
        for (int j = 0; j < 4; ++j) {
            const int dh0 = j * 16 + 4 * g;
            const float4 bv4 = *reinterpret_cast<const float4*>(&bias[colbase + dh0]);
            #pragma unroll
            for (int i = 0; i < 4; ++i) {
                const int m = m0 + wm + i * 16 + lm;
                const int b = m >> 10, t = m & 1023;
                ushort4 o;
                o.x = f2bf((acc[i][j][0] + bv4.x) * scl);
                o.y = f2bf((acc[i][j][1] + bv4.y) * scl);
                o.z = f2bf((acc[i][j][2] + bv4.z) * scl);
                o.w = f2bf((acc[i][j][3] + bv4.w) * scl);
                *reinterpret_cast<ushort4*>(
                    &dst[(((size_t)(b * NHEADS + h)) * SEQ + t) * DHEAD + dh0]) = o;
            }
        }
    } else {
        const int n0 = 2048 + (bx - 16) * 128;  // v rows within Bt
        FP8_KLOOP(As, Bs, A, Bt, n0, acc[i][j] = MFMA_FP8_16x16x128(af[i], bfr[j], acc[i][j]))
        const int vcol = (n0 - 2048) + wn;      // 0..1023 within v
        const int h = vcol >> 6;
        #pragma unroll
        for (int j = 0; j < 4; ++j) {
            const int dh = ((vcol & 63) + j * 16) + lm;
            const float bv = bias[2048 + vcol + j * 16 + lm];
            #pragma unroll
            for (int i = 0; i < 4; ++i) {
                const int t0 = m0 + wm + i * 16 + 4 * g;
                const int b = t0 >> 10, t = t0 & 1023;
                ushort4 o;
                o.x = f2bf(acc[i][j][0] + bv);
                o.y = f2bf(acc[i][j][1] + bv);
                o.z = f2bf(acc[i][j][2] + bv);
                o.w = f2bf(acc[i][j][3] + bv);
                *reinterpret_cast<ushort4*>(
                    &vT[(((size_t)(b * NHEADS + h)) * DHEAD + dh) * SEQ + t]) = o;
            }
        }
    }
}

// ------------------------------------------------------- Proj GEMM (fp8 MX)
// r14: same T1 swizzle; nwg=512, q=64 per XCD (8 A-panels + full 1MB B in L2).
__global__ __launch_bounds__(256, 2) void gemm_proj(
    const u8* __restrict__ A, const u8* __restrict__ Bt,
    const float* __restrict__ bias, const float* __restrict__ z,
    float* __restrict__ out)
{
    __shared__ u8 As[128 * 128];
    __shared__ u8 Bs[128 * 128];
    GEMM_PRELUDE
    const int lin = blockIdx.y * 8 + blockIdx.x;
    const int nl  = (lin & 7) * 64 + (lin >> 3);
    const int n0  = (nl & 7) * 128;
    const int m0  = (nl >> 3) * 128;
    FP8_KLOOP(As, Bs, A, Bt, n0, acc[i][j] = MFMA_FP8_16x16x128(bfr[j], af[i], acc[i][j]))
    #pragma unroll
    for (int j = 0; j < 4; ++j) {
        const int col0 = n0 + wn + j * 16 + 4 * g;
        const float4 bv4 = *reinterpret_cast<const float4*>(&bias[col0]);
        #pragma unroll
        for (int i = 0; i < 4; ++i) {
            const int m = m0 + wm + i * 16 + lm;
            const size_t idx = (size_t)m * D_MODEL + col0;
            const float4 zv = *reinterpret_cast<const float4*>(&z[idx]);
            float4 ov;
            ov.x = zv.x + acc[i][j][0] + bv4.x;
            ov.y = zv.y + acc[i][j][1] + bv4.y;
            ov.z = zv.z + acc[i][j][2] + bv4.z;
            ov.w = zv.w + acc[i][j][3] + bv4.w;
            *reinterpret_cast<float4*>(&out[idx]) = ov;
        }
    }
}

// ------------------------------------------------------------ flash attention
// r10 inner structure (proven): transposed-S, fixed-max softmax, x32 PV via
// tau-permuted V, Schraudolph bf16 exp2 with offset folded into QK MFMA
// C-init, magic-add pack, MFMA-of-ones denominator, setprio; fp8 msa out.
// r15: QBLK 128->64 — occupancy lever. All pipes were <35% with occupancy 30%
// (grid 1024 = 4 blocks/CU cap). 64 q-rows/block -> grid 2048 = 8 blocks/CU,
// WHOLE grid co-resident (VGPR<=64 cap at 8 waves/SIMD ok since per-wave
// state halves; LDS 8x17408=139KB<=160KB). 2x TLP to hide L2 latency; K/V
// staging per CU doubles but VMEM issue was idle. bh=bi&127 keeps all 16
// q-tiles of a head on one XCD (K/V L2-resident).
#define KLD 68   // 64 + 4 pad halves (measured conflict-free r4/r6/r7)
#define EXP2_MAGIC 12582912.0f   // 1.5 * 2^23: low16(bits(x+MAGIC)) = round(x)&0xFFFF

__global__ __launch_bounds__(256, 8) void attn_kernel(
    const u16* __restrict__ Q, const u16* __restrict__ K,
    const u16* __restrict__ Vt, u8* __restrict__ msaf)
{
    __shared__ u16 Ks[64 * KLD];
    __shared__ u16 Vs[64 * KLD];
    const int tid = threadIdx.x, wave = tid >> 6, lane = tid & 63;
    const int lm = lane & 15, g = lane >> 4;
    const int bi = blockIdx.x;
    const int bh = bi & 127;            // same XCD for all q-tiles of a head
    const int q0 = (bi >> 7) * 64;
    const int b = bh >> 4, h = bh & 15;
    const size_t headBase = (size_t)bh * SEQ * DHEAD;
    const u16* Qh = Q + headBase;
    const u16* Kh = K + headBase;
    const u16* Vh = Vt + headBase;      // [64 dh][1024 t]

    const int srow = tid >> 3, sseg = tid & 7;
    const int aA = 16 * (sseg >> 2) + 4 * (sseg & 3);   // tau-permute chunk

    const uint4 onesu = {0x3F803F80u, 0x3F803F80u, 0x3F803F80u, 0x3F803F80u};
    const bf16x8 ONES = __builtin_bit_cast(bf16x8, onesu);
    // exp2 offset folded into the QK accumulator init
    const f32x4 SMINIT = {16250.0f, 16250.0f, 16250.0f, 16250.0f};

    bf16x8 qf[2];
    {
        const u16* qrow = Qh + (size_t)(q0 + wave * 16 + lm) * DHEAD;
        qf[0] = *reinterpret_cast<const bf16x8*>(qrow + g * 8);
        qf[1] = *reinterpret_cast<const bf16x8*>(qrow + 32 + g * 8);
    }

    f32x4 o[4] = {};
    f32x4 lacc = {};

    for (int j0 = 0; j0 < SEQ; j0 += 64) {
        #pragma unroll
        for (int s2 = 0; s2 < 2; ++s2) {
            const int row = srow + 32 * s2;
            *reinterpret_cast<uint4*>(&Ks[row * KLD + sseg * 8]) =
                *reinterpret_cast<const uint4*>(&Kh[(size_t)(j0 + row) * DHEAD + sseg * 8]);
            const u16* vrow = Vh + (size_t)row * SEQ + j0;
            const uint2 va = *reinterpret_cast<const uint2*>(vrow + aA);
            const uint2 vb = *reinterpret_cast<const uint2*>(vrow + 32 + aA);
            uint4 wv; wv.x = va.x; wv.y = va.y; wv.z = vb.x; wv.w = vb.y;
            *reinterpret_cast<uint4*>(&Vs[row * KLD + sseg * 8]) = wv;
        }
        __syncthreads();

        bf16x8 kf0[4], kf1[4];
        #pragma unroll
        for (int ni = 0; ni < 4; ++ni) {
            kf0[ni] = *reinterpret_cast<const bf16x8*>(&Ks[(ni*16 + lm) * KLD + g * 8]);
            kf1[ni] = *reinterpret_cast<const bf16x8*>(&Ks[(ni*16 + lm) * KLD + 32 + g * 8]);
        }

        f32x4 st[4];
        __builtin_amdgcn_s_setprio(1);
        #pragma unroll
        for (int ni = 0; ni < 4; ++ni) {
            st[ni] = __builtin_amdgcn_mfma_f32_16x16x32_bf16(kf0[ni], qf[0], SMINIT, 0, 0, 0);
            st[ni] = __builtin_amdgcn_mfma_f32_16x16x32_bf16(kf1[ni], qf[1], st[ni], 0, 0, 0);
        }
        __builtin_amdgcn_s_setprio(0);
        // magic-add: bits(st + 1.5*2^23) low16 == round(st) & 0xFFFF
        int ip[4][4];
        #pragma unroll
        for (int ni = 0; ni < 4; ++ni)
            #pragma unroll
            for (int r = 0; r < 4; ++r)
                ip[ni][r] = __builtin_bit_cast(int, st[ni][r] + EXP2_MAGIC);
        bf16x8 pfr[2];
        #pragma unroll
        for (int c = 0; c < 2; ++c) {
            uint4 u;
            u.x = pklo(ip[c][1],   ip[c][0]);
            u.y = pklo(ip[c][3],   ip[c][2]);
            u.z = pklo(ip[c+2][1], ip[c+2][0]);
            u.w = pklo(ip[c+2][3], ip[c+2][2]);
            pfr[c] = __builtin_bit_cast(bf16x8, u);
        }
        lacc = __builtin_amdgcn_mfma_f32_16x16x32_bf16(ONES, pfr[0], lacc, 0, 0, 0);
        lacc = __builtin_amdgcn_mfma_f32_16x16x32_bf16(ONES, pfr[1], lacc, 0, 0, 0);

        __builtin_amdgcn_s_setprio(1);
        #pragma unroll
        for (int mt = 0; mt < 4; ++mt) {
            bf16x8 vf0 = *reinterpret_cast<const bf16x8*>(&Vs[(mt*16 + lm) * KLD + g * 8]);
            bf16x8 vf1 = *reinterpret_cast<const bf16x8*>(&Vs[(mt*16 + lm) * KLD + 32 + g * 8]);
            o[mt] = __builtin_amdgcn_mfma_f32_16x16x32_bf16(vf0, pfr[0], o[mt], 0, 0, 0);
            o[mt] = __builtin_amdgcn_mfma_f32_16x16x32_bf16(vf1, pfr[1], o[mt], 0, 0, 0);
        }
        __builtin_amdgcn_s_setprio(0);
        __syncthreads();
    }

    {
        const float inv = 1.0f / lacc[0];
        const int t = q0 + wave * 16 + lm;
        const size_t base = ((size_t)b * SEQ + t) * D_MODEL + h * DHEAD;
        #pragma unroll
        for (int mt = 0; mt < 4; ++mt) {
            const int d0 = mt * 16 + 4 * g;
            int pk = CVT_PK_FP8(o[mt][0] * inv, o[mt][1] * inv, 0, false);
            pk = CVT_PK_FP8(o[mt][2] * inv, o[mt][3] * inv, pk, true);
            *reinterpret_cast<uint32_t*>(&msaf[base + d0]) = (uint32_t)pk;
        }
    }
}

// -------------------------------------------------------------------- launch
extern "C" void kernel_launch(void* const* d_in, const int* in_sizes, int n_in,
                              void* d_out, int out_size, void* d_ws, size_t ws_size,
                              hipStream_t stream) {
    const float* z      = (const float*)d_in[0];
    const float* ln_w   = (const float*)d_in[1];
    const float* ln_b   = (const float*)d_in[2];
    const float* W_qkv  = (const float*)d_in[3];
    const float* b_qkv  = (const float*)d_in[4];
    const float* W_proj = (const float*)d_in[5];
    const float* b_proj = (const float*)d_in[6];
    float* out = (float*)d_out;

    u8* ws = (u8*)d_ws;
    u8*  znf     = ws;                                      // fp8 [8192][1024]   8 MB
    u8*  wqkvTf  = znf + (size_t)MTOT * D_MODEL;            // fp8 [3072][1024]   3 MB
    u8*  wprojTf = wqkvTf + (size_t)3 * D_MODEL * D_MODEL;  // fp8 [1024][1024]   1 MB
    u8*  msaf    = wprojTf + (size_t)D_MODEL * D_MODEL;     // fp8 [8192][1024]   8 MB
    u16* q       = (u16*)(msaf + (size_t)MTOT * D_MODEL);   // bf16 [b,h,t,dh]   16 MB
    u16* k       = q + (size_t)MTOT * D_MODEL;              // bf16 [b,h,t,dh]   16 MB
    u16* vT      = k + (size_t)MTOT * D_MODEL;              // bf16 [b,h,dh,t]   16 MB

    prep_inputs<<<MTOT + 4096, 256, 0, stream>>>(
        z, ln_w, ln_b, (uint32_t*)znf, W_qkv, W_proj, wqkvTf, wprojTf);
    gemm_qkv<<<dim3(24, MTOT / 128), 256, 0, stream>>>(znf, wqkvTf, b_qkv, q, k, vT);
    attn_kernel<<<BATCH * NHEADS * (SEQ / 64), 256, 0, stream>>>(q, k, vT, msaf);
    gemm_proj<<<dim3(D_MODEL / 128, MTOT / 128), 256, 0, stream>>>(
        msaf, wprojTf, b_proj, z, out);
}

// Round 10
// 230.215 us; speedup vs baseline: 1.5613x; 1.5613x over previous
//
#include <hip/hip_runtime.h>
#include <stdint.h>

typedef unsigned short u16;
typedef uint8_t u8;
typedef __bf16 bf16x8 __attribute__((ext_vector_type(8)));
typedef float f32x4 __attribute__((ext_vector_type(4)));
typedef int i32x8 __attribute__((ext_vector_type(8)));

#define D_MODEL 1024
#define NHEADS  16
#define DHEAD   64
#define BATCH   8
#define SEQ     1024
#define MTOT    (BATCH*SEQ)          // 8192 rows

#define GPTR(p) ((const __attribute__((address_space(1))) void*)(p))
#define LPTR(p) ((__attribute__((address_space(3))) void*)(p))

// Device-only builtins (host pass just needs to parse — r2 lesson)
#if defined(__HIP_DEVICE_COMPILE__)
  #define MFMA_FP8_16x16x128(a, b, c) \
      __builtin_amdgcn_mfma_scale_f32_16x16x128_f8f6f4((a), (b), (c), 0, 0, 0, 127, 0, 127)
  #define CVT_PK_FP8(a, b, old, w) __builtin_amdgcn_cvt_pk_fp8_f32((a), (b), (old), (w))
#else
  #define MFMA_FP8_16x16x128(a, b, c) (c)
  #define CVT_PK_FP8(a, b, old, w) (0)
#endif

__device__ __forceinline__ u16 f2bf(float f) {
    union { float f; uint32_t u; } v; v.f = f;
    uint32_t u = v.u;
    u += 0x7fffu + ((u >> 16) & 1u);  // RNE
    return (u16)(u >> 16);
}

// pack low16 of two ints: result = [i1.low16 : i0.low16]
__device__ __forceinline__ uint32_t pklo(int i1, int i0) {
    return __builtin_amdgcn_perm((uint32_t)i1, (uint32_t)i0, 0x05040100u);
}

// --------------- merged prep: LayerNorm->fp8 (blocks 0..8191) and
//                 weight transpose->fp8 (blocks 8192..12287)
__global__ __launch_bounds__(256) void prep_inputs(
    const float* __restrict__ z, const float* __restrict__ w,
    const float* __restrict__ b, uint32_t* __restrict__ znf,
    const float* __restrict__ Wqkv, const float* __restrict__ Wproj,
    u8* __restrict__ outQkv, u8* __restrict__ outProj)
{
    __shared__ float red[8];
    __shared__ u8 tile[32][36];
    const int bid = blockIdx.x;
    const int t = threadIdx.x;
    if (bid < MTOT) {
        // ---- LayerNorm row
        const int row = bid;
        const float4 v = reinterpret_cast<const float4*>(z + (size_t)row * D_MODEL)[t];
        float s  = v.x + v.y + v.z + v.w;
        float s2 = v.x*v.x + v.y*v.y + v.z*v.z + v.w*v.w;
        #pragma unroll
        for (int off = 32; off; off >>= 1) {
            s  += __shfl_down(s,  off, 64);
            s2 += __shfl_down(s2, off, 64);
        }
        const int wave = t >> 6, lane = t & 63;
        if (lane == 0) { red[wave] = s; red[wave + 4] = s2; }
        __syncthreads();
        if (t == 0) {
            float ts  = red[0] + red[1] + red[2] + red[3];
            float ts2 = red[4] + red[5] + red[6] + red[7];
            float mu  = ts * (1.0f / D_MODEL);
            float var = ts2 * (1.0f / D_MODEL) - mu * mu;
            red[0] = mu; red[1] = rsqrtf(var + 1e-5f);
        }
        __syncthreads();
        const float mu = red[0], rstd = red[1];
        const float4 wv = reinterpret_cast<const float4*>(w)[t];
        const float4 bv = reinterpret_cast<const float4*>(b)[t];
        const float x0 = (v.x - mu) * rstd * wv.x + bv.x;
        const float x1 = (v.y - mu) * rstd * wv.y + bv.y;
        const float x2 = (v.z - mu) * rstd * wv.z + bv.z;
        const float x3 = (v.w - mu) * rstd * wv.w + bv.w;
        int pk = CVT_PK_FP8(x0, x1, 0, false);
        pk = CVT_PK_FP8(x2, x3, pk, true);
        znf[(size_t)row * (D_MODEL / 4) + t] = (uint32_t)pk;
    } else {
        // ---- weight transpose + fp8 cast (32x32 tile)
        const int bx = bid - MTOT;            // 0..4095
        const int cx = bx & 127;              // 128 column-tiles
        const int r0 = (bx >> 7) * 32;        // 32 row-tiles
        const float* in; u8* out; int C;
        if (cx < 96) { in = Wqkv;  out = outQkv;  C = 3072; }
        else         { in = Wproj; out = outProj; C = 1024; }
        const int c0 = (cx < 96 ? cx : cx - 96) * 32;
        const int tx = t & 31, ty = t >> 5;   // 32x8
        #pragma unroll
        for (int i = 0; i < 4; ++i) {
            const float f = in[(size_t)(r0 + ty + i*8) * C + c0 + tx];
            tile[ty + i*8][tx] = (u8)(CVT_PK_FP8(f, 0.f, 0, false) & 0xFF);
        }
        __syncthreads();
        #pragma unroll
        for (int i = 0; i < 4; ++i)
            out[(size_t)(c0 + ty + i*8) * D_MODEL + r0 + tx] = tile[tx][ty + i*8];
    }
}

// q scale: 0.125 * log2(e) * 128 — the x128 of the Schraudolph exp2 is folded
// into the q values themselves; the +16250 offset is folded into the QK MFMA
// C-operand (SMINIT in attn_kernel). So the per-score softmax work is a single
// magic-add (v_add_f32) + perm pack.
#define QSCALE 23.0831207f

// ---------------------------------------------------------- fp8 GEMM mainloop
// r10 single-buffer form (proven): 128x128 tile, K-tile=128B, 4 waves;
// XOR swizzle; global_load_lds width-16. (2-phase dbuf tested r4: neutral,
// matches the m99/m100 known-null; costs LDS.)
#define GEMM_PRELUDE                                                            \
    const int tid = threadIdx.x;                                                \
    const int wave = tid >> 6, lane = tid & 63;                                 \
    const int lm = lane & 15, g = lane >> 4;                                    \
    const int wm = (wave >> 1) * 64, wn = (wave & 1) * 64;                      \
    const int srow = tid >> 3;                                                  \
    const int sseg = tid & 7;                                                   \
    const int sgcol = (sseg ^ (srow & 7)) * 16;                                 \
    const int xl = lm & 7;                                                      \
    const int ca0 = ((2 * g) ^ xl) * 16;                                        \
    const int ca1 = ((2 * g + 1) ^ xl) * 16;

#define FP8_KLOOP(As_, Bs_, A_, Bt_, n0_, MFMA_STMT)                            \
    f32x4 acc[4][4] = {};                                                       \
    for (int k0 = 0; k0 < D_MODEL; k0 += 128) {                                 \
        _Pragma("unroll")                                                       \
        for (int c = 0; c < 4; ++c) {                                           \
            const int r = srow + c * 32;                                        \
            __builtin_amdgcn_global_load_lds(                                   \
                GPTR(&A_[(size_t)(m0 + r) * D_MODEL + k0 + sgcol]),             \
                LPTR(&As_[r * 128 + sseg * 16]), 16, 0, 0);                     \
            __builtin_amdgcn_global_load_lds(                                   \
                GPTR(&Bt_[(size_t)((n0_) + r) * D_MODEL + k0 + sgcol]),         \
                LPTR(&Bs_[r * 128 + sseg * 16]), 16, 0, 0);                     \
        }                                                                       \
        __syncthreads();                                                        \
        i32x8 af[4], bfr[4];                                                    \
        _Pragma("unroll")                                                       \
        for (int i = 0; i < 4; ++i) {                                           \
            const uint4 alo = *reinterpret_cast<const uint4*>(&As_[(wm + i*16 + lm) * 128 + ca0]); \
            const uint4 ahi = *reinterpret_cast<const uint4*>(&As_[(wm + i*16 + lm) * 128 + ca1]); \
            af[i][0] = alo.x; af[i][1] = alo.y; af[i][2] = alo.z; af[i][3] = alo.w; \
            af[i][4] = ahi.x; af[i][5] = ahi.y; af[i][6] = ahi.z; af[i][7] = ahi.w; \
            const uint4 blo = *reinterpret_cast<const uint4*>(&Bs_[(wn + i*16 + lm) * 128 + ca0]); \
            const uint4 bhi = *reinterpret_cast<const uint4*>(&Bs_[(wn + i*16 + lm) * 128 + ca1]); \
            bfr[i][0] = blo.x; bfr[i][1] = blo.y; bfr[i][2] = blo.z; bfr[i][3] = blo.w; \
            bfr[i][4] = bhi.x; bfr[i][5] = bhi.y; bfr[i][6] = bhi.z; bfr[i][7] = bhi.w; \
        }                                                                       \
        _Pragma("unroll")                                                       \
        for (int i = 0; i < 4; ++i)                                             \
            _Pragma("unroll")                                                   \
            for (int j = 0; j < 4; ++j)                                         \
                MFMA_STMT;                                                      \
        __syncthreads();                                                        \
    }

// -------------------------------------------- merged QKV GEMM (r13/r14)
// grid x: 0..15 = q/k columns (swapped-operand MFMA, lane owns 4 dh);
//         16..23 = v columns (unswapped, writes vT[b,h,dh,t] direct).
// r14: T1 XCD-aware bijective swizzle — each XCD gets 192 consecutive tiles
// (8 A-panels x full B sweep ~= 4MB = its L2). nwg=1536 %8==0 -> valid.
__global__ __launch_bounds__(256, 2) void gemm_qkv(
    const u8* __restrict__ A, const u8* __restrict__ Bt,
    const float* __restrict__ bias,
    u16* __restrict__ q, u16* __restrict__ k, u16* __restrict__ vT)
{
    __shared__ u8 As[128 * 128];
    __shared__ u8 Bs[128 * 128];
    GEMM_PRELUDE
    const int lin = blockIdx.y * 24 + blockIdx.x;   // HW dispatch order (x fastest)
    const int nl  = (lin & 7) * 192 + (lin >> 3);   // XCD-contiguous remap
    const int bx  = nl % 24;
    const int m0  = (nl / 24) * 128;
    if (bx < 16) {
        const int n0 = bx * 128;
        FP8_KLOOP(As, Bs, A, Bt, n0, acc[i][j] = MFMA_FP8_16x16x128(bfr[j], af[i], acc[i][j]))
        const int colbase = n0 + wn;
        const int sel = colbase >> 10;          // 0=q 1=k
        const int h = (colbase & 1023) >> 6;
        u16* dst = (sel == 0) ? q : k;
        const float scl = (sel == 0) ? QSCALE : 1.0f;
        #pragma unroll
        for (int j = 0; j < 4; ++j) {
            const int dh0 = j * 16 + 4 * g;
            const float4 bv4 = *reinterpret_cast<const float4*>(&bias[colbase + dh0]);
            #pragma unroll
            for (int i = 0; i < 4; ++i) {
                const int m = m0 + wm + i * 16 + lm;
                const int b = m >> 10, t = m & 1023;
                ushort4 o;
                o.x = f2bf((acc[i][j][0] + bv4.x) * scl);
                o.y = f2bf((acc[i][j][1] + bv4.y) * scl);
                o.z = f2bf((acc[i][j][2] + bv4.z) * scl);
                o.w = f2bf((acc[i][j][3] + bv4.w) * scl);
                *reinterpret_cast<ushort4*>(
                    &dst[(((size_t)(b * NHEADS + h)) * SEQ + t) * DHEAD + dh0]) = o;
            }
        }
    } else {
        const int n0 = 2048 + (bx - 16) * 128;  // v rows within Bt
        FP8_KLOOP(As, Bs, A, Bt, n0, acc[i][j] = MFMA_FP8_16x16x128(af[i], bfr[j], acc[i][j]))
        const int vcol = (n0 - 2048) + wn;      // 0..1023 within v
        const int h = vcol >> 6;
        #pragma unroll
        for (int j = 0; j < 4; ++j) {
            const int dh = ((vcol & 63) + j * 16) + lm;
            const float bv = bias[2048 + vcol + j * 16 + lm];
            #pragma unroll
            for (int i = 0; i < 4; ++i) {
                const int t0 = m0 + wm + i * 16 + 4 * g;
                const int b = t0 >> 10, t = t0 & 1023;
                ushort4 o;
                o.x = f2bf(acc[i][j][0] + bv);
                o.y = f2bf(acc[i][j][1] + bv);
                o.z = f2bf(acc[i][j][2] + bv);
                o.w = f2bf(acc[i][j][3] + bv);
                *reinterpret_cast<ushort4*>(
                    &vT[(((size_t)(b * NHEADS + h)) * DHEAD + dh) * SEQ + t]) = o;
            }
        }
    }
}

// ------------------------------------------------------- Proj GEMM (fp8 MX)
// r14: same T1 swizzle; nwg=512, q=64 per XCD (8 A-panels + full 1MB B in L2).
__global__ __launch_bounds__(256, 2) void gemm_proj(
    const u8* __restrict__ A, const u8* __restrict__ Bt,
    const float* __restrict__ bias, const float* __restrict__ z,
    float* __restrict__ out)
{
    __shared__ u8 As[128 * 128];
    __shared__ u8 Bs[128 * 128];
    GEMM_PRELUDE
    const int lin = blockIdx.y * 8 + blockIdx.x;
    const int nl  = (lin & 7) * 64 + (lin >> 3);
    const int n0  = (nl & 7) * 128;
    const int m0  = (nl >> 3) * 128;
    FP8_KLOOP(As, Bs, A, Bt, n0, acc[i][j] = MFMA_FP8_16x16x128(bfr[j], af[i], acc[i][j]))
    #pragma unroll
    for (int j = 0; j < 4; ++j) {
        const int col0 = n0 + wn + j * 16 + 4 * g;
        const float4 bv4 = *reinterpret_cast<const float4*>(&bias[col0]);
        #pragma unroll
        for (int i = 0; i < 4; ++i) {
            const int m = m0 + wm + i * 16 + lm;
            const size_t idx = (size_t)m * D_MODEL + col0;
            const float4 zv = *reinterpret_cast<const float4*>(&z[idx]);
            float4 ov;
            ov.x = zv.x + acc[i][j][0] + bv4.x;
            ov.y = zv.y + acc[i][j][1] + bv4.y;
            ov.z = zv.z + acc[i][j][2] + bv4.z;
            ov.w = zv.w + acc[i][j][3] + bv4.w;
            *reinterpret_cast<float4*>(&out[idx]) = ov;
        }
    }
}

// ------------------------------------------------------------ flash attention
// r10 inner structure (proven 43us): transposed-S, fixed-max softmax, 128
// q-rows/block, x32 PV via tau-permuted V, Schraudolph bf16 exp2 with offset
// folded into QK MFMA C-init, magic-add pack, MFMA-of-ones denominator,
// setprio; fp8 msa out.
// r16: T14 async-stage + LDS dbuf RETRY with the spill fixed. r11 spilled
// because __launch_bounds__(256,4) capped VGPR at 64 — no room for the 16
// staging regs (193MB scratch). Grid=1024 caps residency at 4 blocks/CU
// ANYWAY, so (256,2) [VGPR cap 128] costs zero occupancy and fits staging.
// r15 lesson: tight launch_bounds = spill trigger on this kernel.
#define KLD 68   // 64 + 4 pad halves (measured conflict-free r4/r6/r7)
#define TILE_HALF (64 * KLD)     // u16 elements per K (or V) buffer
#define EXP2_MAGIC 12582912.0f   // 1.5 * 2^23: low16(bits(x+MAGIC)) = round(x)&0xFFFF

__global__ __launch_bounds__(256, 2) void attn_kernel(
    const u16* __restrict__ Q, const u16* __restrict__ K,
    const u16* __restrict__ Vt, u8* __restrict__ msaf)
{
    __shared__ u16 Ks[2 * TILE_HALF];
    __shared__ u16 Vs[2 * TILE_HALF];
    const int tid = threadIdx.x, wave = tid >> 6, lane = tid & 63;
    const int lm = lane & 15, g = lane >> 4;
    const int bi = blockIdx.x;
    const int bh = bi & 127;            // same XCD for all q-tiles of a head
    const int q0 = (bi >> 7) * 128;
    const int b = bh >> 4, h = bh & 15;
    const size_t headBase = (size_t)bh * SEQ * DHEAD;
    const u16* Qh = Q + headBase;
    const u16* Kh = K + headBase;
    const u16* Vh = Vt + headBase;      // [64 dh][1024 t]

    const int srow = tid >> 3, sseg = tid & 7;
    const int aA = 16 * (sseg >> 2) + 4 * (sseg & 3);   // tau-permute chunk

    const uint4 onesu = {0x3F803F80u, 0x3F803F80u, 0x3F803F80u, 0x3F803F80u};
    const bf16x8 ONES = __builtin_bit_cast(bf16x8, onesu);
    // exp2 offset folded into the QK accumulator init
    const f32x4 SMINIT = {16250.0f, 16250.0f, 16250.0f, 16250.0f};

    bf16x8 qf[2][2];
    #pragma unroll
    for (int s = 0; s < 2; ++s) {
        const u16* qrow = Qh + (size_t)(q0 + s * 64 + wave * 16 + lm) * DHEAD;
        qf[s][0] = *reinterpret_cast<const bf16x8*>(qrow + g * 8);
        qf[s][1] = *reinterpret_cast<const bf16x8*>(qrow + 32 + g * 8);
    }

    // ---- staging: global->reg (issue early) ... reg->LDS (write late)
    uint4 kr[2], vr[2];
    #define STAGE_LOAD(jj)                                                      \
        _Pragma("unroll")                                                       \
        for (int s2 = 0; s2 < 2; ++s2) {                                        \
            const int row = srow + 32 * s2;                                     \
            kr[s2] = *reinterpret_cast<const uint4*>(                           \
                &Kh[(size_t)((jj) + row) * DHEAD + sseg * 8]);                  \
            const u16* vrow = Vh + (size_t)row * SEQ + (jj);                    \
            const uint2 va = *reinterpret_cast<const uint2*>(vrow + aA);        \
            const uint2 vb = *reinterpret_cast<const uint2*>(vrow + 32 + aA);   \
            vr[s2].x = va.x; vr[s2].y = va.y; vr[s2].z = vb.x; vr[s2].w = vb.y; \
        }
    #define STAGE_WRITE(bo_)                                                    \
        _Pragma("unroll")                                                       \
        for (int s2 = 0; s2 < 2; ++s2) {                                        \
            const int row = srow + 32 * s2;                                     \
            *reinterpret_cast<uint4*>(&Ks[(bo_) + row * KLD + sseg * 8]) = kr[s2]; \
            *reinterpret_cast<uint4*>(&Vs[(bo_) + row * KLD + sseg * 8]) = vr[s2]; \
        }

    f32x4 o[2][4] = {};
    f32x4 lacc[2] = {};

    STAGE_LOAD(0)
    STAGE_WRITE(0)
    int cur = 0;

    for (int it = 0; it < SEQ / 64; ++it) {
        const int jn = ((it + 1) & (SEQ / 64 - 1)) * 64;   // wrap: branch-free
        STAGE_LOAD(jn)                 // issue next tile's loads NOW
        __syncthreads();               // buf[cur] writes from prev iter visible
        const int bo = cur * TILE_HALF;

        bf16x8 kf0[4], kf1[4];
        #pragma unroll
        for (int ni = 0; ni < 4; ++ni) {
            kf0[ni] = *reinterpret_cast<const bf16x8*>(&Ks[bo + (ni*16 + lm) * KLD + g * 8]);
            kf1[ni] = *reinterpret_cast<const bf16x8*>(&Ks[bo + (ni*16 + lm) * KLD + 32 + g * 8]);
        }

        bf16x8 pfr[2][2];
        #pragma unroll
        for (int s = 0; s < 2; ++s) {
            f32x4 st[4];
            __builtin_amdgcn_s_setprio(1);
            #pragma unroll
            for (int ni = 0; ni < 4; ++ni) {
                st[ni] = __builtin_amdgcn_mfma_f32_16x16x32_bf16(kf0[ni], qf[s][0], SMINIT, 0, 0, 0);
                st[ni] = __builtin_amdgcn_mfma_f32_16x16x32_bf16(kf1[ni], qf[s][1], st[ni], 0, 0, 0);
            }
            __builtin_amdgcn_s_setprio(0);
            // magic-add: bits(st + 1.5*2^23) low16 == round(st) & 0xFFFF
            int ip[4][4];
            #pragma unroll
            for (int ni = 0; ni < 4; ++ni)
                #pragma unroll
                for (int r = 0; r < 4; ++r)
                    ip[ni][r] = __builtin_bit_cast(int, st[ni][r] + EXP2_MAGIC);
            #pragma unroll
            for (int c = 0; c < 2; ++c) {
                uint4 u;
                u.x = pklo(ip[c][1],   ip[c][0]);
                u.y = pklo(ip[c][3],   ip[c][2]);
                u.z = pklo(ip[c+2][1], ip[c+2][0]);
                u.w = pklo(ip[c+2][3], ip[c+2][2]);
                pfr[s][c] = __builtin_bit_cast(bf16x8, u);
            }
            lacc[s] = __builtin_amdgcn_mfma_f32_16x16x32_bf16(ONES, pfr[s][0], lacc[s], 0, 0, 0);
            lacc[s] = __builtin_amdgcn_mfma_f32_16x16x32_bf16(ONES, pfr[s][1], lacc[s], 0, 0, 0);
        }

        __builtin_amdgcn_s_setprio(1);
        #pragma unroll
        for (int mt = 0; mt < 4; ++mt) {
            bf16x8 vf0 = *reinterpret_cast<const bf16x8*>(&Vs[bo + (mt*16 + lm) * KLD + g * 8]);
            bf16x8 vf1 = *reinterpret_cast<const bf16x8*>(&Vs[bo + (mt*16 + lm) * KLD + 32 + g * 8]);
            #pragma unroll
            for (int s = 0; s < 2; ++s) {
                o[s][mt] = __builtin_amdgcn_mfma_f32_16x16x32_bf16(vf0, pfr[s][0], o[s][mt], 0, 0, 0);
                o[s][mt] = __builtin_amdgcn_mfma_f32_16x16x32_bf16(vf1, pfr[s][1], o[s][mt], 0, 0, 0);
            }
        }
        __builtin_amdgcn_s_setprio(0);

        // write next tile into the other buffer; next iter's barrier fences it
        STAGE_WRITE((cur ^ 1) * TILE_HALF)
        cur ^= 1;
    }

    #pragma unroll
    for (int s = 0; s < 2; ++s) {
        const float inv = 1.0f / lacc[s][0];
        const int t = q0 + s * 64 + wave * 16 + lm;
        const size_t base = ((size_t)b * SEQ + t) * D_MODEL + h * DHEAD;
        #pragma unroll
        for (int mt = 0; mt < 4; ++mt) {
            const int d0 = mt * 16 + 4 * g;
            int pk = CVT_PK_FP8(o[s][mt][0] * inv, o[s][mt][1] * inv, 0, false);
            pk = CVT_PK_FP8(o[s][mt][2] * inv, o[s][mt][3] * inv, pk, true);
            *reinterpret_cast<uint32_t*>(&msaf[base + d0]) = (uint32_t)pk;
        }
    }
}

// -------------------------------------------------------------------- launch
extern "C" void kernel_launch(void* const* d_in, const int* in_sizes, int n_in,
                              void* d_out, int out_size, void* d_ws, size_t ws_size,
                              hipStream_t stream) {
    const float* z      = (const float*)d_in[0];
    const float* ln_w   = (const float*)d_in[1];
    const float* ln_b   = (const float*)d_in[2];
    const float* W_qkv  = (const float*)d_in[3];
    const float* b_qkv  = (const float*)d_in[4];
    const float* W_proj = (const float*)d_in[5];
    const float* b_proj = (const float*)d_in[6];
    float* out = (float*)d_out;

    u8* ws = (u8*)d_ws;
    u8*  znf     = ws;                                      // fp8 [8192][1024]   8 MB
    u8*  wqkvTf  = znf + (size_t)MTOT * D_MODEL;            // fp8 [3072][1024]   3 MB
    u8*  wprojTf = wqkvTf + (size_t)3 * D_MODEL * D_MODEL;  // fp8 [1024][1024]   1 MB
    u8*  msaf    = wprojTf + (size_t)D_MODEL * D_MODEL;     // fp8 [8192][1024]   8 MB
    u16* q       = (u16*)(msaf + (size_t)MTOT * D_MODEL);   // bf16 [b,h,t,dh]   16 MB
    u16* k       = q + (size_t)MTOT * D_MODEL;              // bf16 [b,h,t,dh]   16 MB
    u16* vT      = k + (size_t)MTOT * D_MODEL;              // bf16 [b,h,dh,t]   16 MB

    prep_inputs<<<MTOT + 4096, 256, 0, stream>>>(
        z, ln_w, ln_b, (uint32_t*)znf, W_qkv, W_proj, wqkvTf, wprojTf);
    gemm_qkv<<<dim3(24, MTOT / 128), 256, 0, stream>>>(znf, wqkvTf, b_qkv, q, k, vT);
    attn_kernel<<<BATCH * NHEADS * (SEQ / 128), 256, 0, stream>>>(q, k, vT, msaf);
    gemm_proj<<<dim3(D_MODEL / 128, MTOT / 128), 256, 0, stream>>>(
        msaf, wprojTf, b_proj, z, out);
}

// Round 12
// 215.272 us; speedup vs baseline: 1.6697x; 1.0694x over previous
//
#include <hip/hip_runtime.h>
#include <stdint.h>

typedef unsigned short u16;
typedef uint8_t u8;
typedef __bf16 bf16x8 __attribute__((ext_vector_type(8)));
typedef float f32x4 __attribute__((ext_vector_type(4)));
typedef int i32x8 __attribute__((ext_vector_type(8)));

#define D_MODEL 1024
#define NHEADS  16
#define DHEAD   64
#define BATCH   8
#define SEQ     1024
#define MTOT    (BATCH*SEQ)          // 8192 rows

#define GPTR(p) ((const __attribute__((address_space(1))) void*)(p))
#define LPTR(p) ((__attribute__((address_space(3))) void*)(p))

// Device-only builtins (host pass just needs to parse — r2 lesson)
#if defined(__HIP_DEVICE_COMPILE__)
  #define MFMA_FP8_16x16x128(a, b, c) \
      __builtin_amdgcn_mfma_scale_f32_16x16x128_f8f6f4((a), (b), (c), 0, 0, 0, 127, 0, 127)
  #define CVT_PK_FP8(a, b, old, w) __builtin_amdgcn_cvt_pk_fp8_f32((a), (b), (old), (w))
#else
  #define MFMA_FP8_16x16x128(a, b, c) (c)
  #define CVT_PK_FP8(a, b, old, w) (0)
#endif

__device__ __forceinline__ u16 f2bf(float f) {
    union { float f; uint32_t u; } v; v.f = f;
    uint32_t u = v.u;
    u += 0x7fffu + ((u >> 16) & 1u);  // RNE
    return (u16)(u >> 16);
}

// pack low16 of two ints: result = [i1.low16 : i0.low16]
__device__ __forceinline__ uint32_t pklo(int i1, int i0) {
    return __builtin_amdgcn_perm((uint32_t)i1, (uint32_t)i0, 0x05040100u);
}

// --------------- merged prep: LayerNorm->fp8 (blocks 0..8191) and
//                 weight transpose->fp8 (blocks 8192..12287)
__global__ __launch_bounds__(256) void prep_inputs(
    const float* __restrict__ z, const float* __restrict__ w,
    const float* __restrict__ b, uint32_t* __restrict__ znf,
    const float* __restrict__ Wqkv, const float* __restrict__ Wproj,
    u8* __restrict__ outQkv, u8* __restrict__ outProj)
{
    __shared__ float red[8];
    __shared__ u8 tile[32][36];
    const int bid = blockIdx.x;
    const int t = threadIdx.x;
    if (bid < MTOT) {
        // ---- LayerNorm row
        const int row = bid;
        const float4 v = reinterpret_cast<const float4*>(z + (size_t)row * D_MODEL)[t];
        float s  = v.x + v.y + v.z + v.w;
        float s2 = v.x*v.x + v.y*v.y + v.z*v.z + v.w*v.w;
        #pragma unroll
        for (int off = 32; off; off >>= 1) {
            s  += __shfl_down(s,  off, 64);
            s2 += __shfl_down(s2, off, 64);
        }
        const int wave = t >> 6, lane = t & 63;
        if (lane == 0) { red[wave] = s; red[wave + 4] = s2; }
        __syncthreads();
        if (t == 0) {
            float ts  = red[0] + red[1] + red[2] + red[3];
            float ts2 = red[4] + red[5] + red[6] + red[7];
            float mu  = ts * (1.0f / D_MODEL);
            float var = ts2 * (1.0f / D_MODEL) - mu * mu;
            red[0] = mu; red[1] = rsqrtf(var + 1e-5f);
        }
        __syncthreads();
        const float mu = red[0], rstd = red[1];
        const float4 wv = reinterpret_cast<const float4*>(w)[t];
        const float4 bv = reinterpret_cast<const float4*>(b)[t];
        const float x0 = (v.x - mu) * rstd * wv.x + bv.x;
        const float x1 = (v.y - mu) * rstd * wv.y + bv.y;
        const float x2 = (v.z - mu) * rstd * wv.z + bv.z;
        const float x3 = (v.w - mu) * rstd * wv.w + bv.w;
        int pk = CVT_PK_FP8(x0, x1, 0, false);
        pk = CVT_PK_FP8(x2, x3, pk, true);
        znf[(size_t)row * (D_MODEL / 4) + t] = (uint32_t)pk;
    } else {
        // ---- weight transpose + fp8 cast (32x32 tile)
        const int bx = bid - MTOT;            // 0..4095
        const int cx = bx & 127;              // 128 column-tiles
        const int r0 = (bx >> 7) * 32;        // 32 row-tiles
        const float* in; u8* out; int C;
        if (cx < 96) { in = Wqkv;  out = outQkv;  C = 3072; }
        else         { in = Wproj; out = outProj; C = 1024; }
        const int c0 = (cx < 96 ? cx : cx - 96) * 32;
        const int tx = t & 31, ty = t >> 5;   // 32x8
        #pragma unroll
        for (int i = 0; i < 4; ++i) {
            const float f = in[(size_t)(r0 + ty + i*8) * C + c0 + tx];
            tile[ty + i*8][tx] = (u8)(CVT_PK_FP8(f, 0.f, 0, false) & 0xFF);
        }
        __syncthreads();
        #pragma unroll
        for (int i = 0; i < 4; ++i)
            out[(size_t)(c0 + ty + i*8) * D_MODEL + r0 + tx] = tile[tx][ty + i*8];
    }
}

// q scale: 0.125 * log2(e) * 128 — the x128 of the Schraudolph exp2 is folded
// into the q values themselves; the +16250 offset is folded into the QK MFMA
// C-operand (SMINIT in attn_kernel). So the per-score softmax work is a single
// magic-add (v_add_f32) + perm pack.
#define QSCALE 23.0831207f

// ---------------------------------------------------------- fp8 GEMM mainloop
// r10 single-buffer form (proven): 128x128 tile, K-tile=128B, 4 waves;
// XOR swizzle; global_load_lds width-16. (2-phase dbuf tested r4: neutral,
// matches the m99/m100 known-null; costs LDS.)
#define GEMM_PRELUDE                                                            \
    const int tid = threadIdx.x;                                                \
    const int wave = tid >> 6, lane = tid & 63;                                 \
    const int lm = lane & 15, g = lane >> 4;                                    \
    const int wm = (wave >> 1) * 64, wn = (wave & 1) * 64;                      \
    const int srow = tid >> 3;                                                  \
    const int sseg = tid & 7;                                                   \
    const int sgcol = (sseg ^ (srow & 7)) * 16;                                 \
    const int xl = lm & 7;                                                      \
    const int ca0 = ((2 * g) ^ xl) * 16;                                        \
    const int ca1 = ((2 * g + 1) ^ xl) * 16;

#define FP8_KLOOP(As_, Bs_, A_, Bt_, n0_, MFMA_STMT)                            \
    f32x4 acc[4][4] = {};                                                       \
    for (int k0 = 0; k0 < D_MODEL; k0 += 128) {                                 \
        _Pragma("unroll")                                                       \
        for (int c = 0; c < 4; ++c) {                                           \
            const int r = srow + c * 32;                                        \
            __builtin_amdgcn_global_load_lds(                                   \
                GPTR(&A_[(size_t)(m0 + r) * D_MODEL + k0 + sgcol]),             \
                LPTR(&As_[r * 128 + sseg * 16]), 16, 0, 0);                     \
            __builtin_amdgcn_global_load_lds(                                   \
                GPTR(&Bt_[(size_t)((n0_) + r) * D_MODEL + k0 + sgcol]),         \
                LPTR(&Bs_[r * 128 + sseg * 16]), 16, 0, 0);                     \
        }                                                                       \
        __syncthreads();                                                        \
        i32x8 af[4], bfr[4];                                                    \
        _Pragma("unroll")                                                       \
        for (int i = 0; i < 4; ++i) {                                           \
            const uint4 alo = *reinterpret_cast<const uint4*>(&As_[(wm + i*16 + lm) * 128 + ca0]); \
            const uint4 ahi = *reinterpret_cast<const uint4*>(&As_[(wm + i*16 + lm) * 128 + ca1]); \
            af[i][0] = alo.x; af[i][1] = alo.y; af[i][2] = alo.z; af[i][3] = alo.w; \
            af[i][4] = ahi.x; af[i][5] = ahi.y; af[i][6] = ahi.z; af[i][7] = ahi.w; \
            const uint4 blo = *reinterpret_cast<const uint4*>(&Bs_[(wn + i*16 + lm) * 128 + ca0]); \
            const uint4 bhi = *reinterpret_cast<const uint4*>(&Bs_[(wn + i*16 + lm) * 128 + ca1]); \
            bfr[i][0] = blo.x; bfr[i][1] = blo.y; bfr[i][2] = blo.z; bfr[i][3] = blo.w; \
            bfr[i][4] = bhi.x; bfr[i][5] = bhi.y; bfr[i][6] = bhi.z; bfr[i][7] = bhi.w; \
        }                                                                       \
        _Pragma("unroll")                                                       \
        for (int i = 0; i < 4; ++i)                                             \
            _Pragma("unroll")                                                   \
            for (int j = 0; j < 4; ++j)                                         \
                MFMA_STMT;                                                      \
        __syncthreads();                                                        \
    }

// -------------------------------------------- merged QKV GEMM (r13/r14)
// grid x: 0..15 = q/k columns (swapped-operand MFMA, lane owns 4 dh);
//         16..23 = v columns (unswapped, writes vT[b,h,dh,t] direct).
// r14: T1 XCD-aware bijective swizzle — each XCD gets 192 consecutive tiles
// (8 A-panels x full B sweep ~= 4MB = its L2). nwg=1536 %8==0 -> valid.
__global__ __launch_bounds__(256, 2) void gemm_qkv(
    const u8* __restrict__ A, const u8* __restrict__ Bt,
    const float* __restrict__ bias,
    u16* __restrict__ q, u16* __restrict__ k, u16* __restrict__ vT)
{
    __shared__ u8 As[128 * 128];
    __shared__ u8 Bs[128 * 128];
    GEMM_PRELUDE
    const int lin = blockIdx.y * 24 + blockIdx.x;   // HW dispatch order (x fastest)
    const int nl  = (lin & 7) * 192 + (lin >> 3);   // XCD-contiguous remap
    const int bx  = nl % 24;
    const int m0  = (nl / 24) * 128;
    if (bx < 16) {
        const int n0 = bx * 128;
        FP8_KLOOP(As, Bs, A, Bt, n0, acc[i][j] = MFMA_FP8_16x16x128(bfr[j], af[i], acc[i][j]))
        const int colbase = n0 + wn;
        const int sel = colbase >> 10;          // 0=q 1=k
        const int h = (colbase & 1023) >> 6;
        u16* dst = (sel == 0) ? q : k;
        const float scl = (sel == 0) ? QSCALE : 1.0f;
        #pragma unroll
        for (int j = 0; j < 4; ++j) {
            const int dh0 = j * 16 + 4 * g;
            const float4 bv4 = *reinterpret_cast<const float4*>(&bias[colbase + dh0]);
            #pragma unroll
            for (int i = 0; i < 4; ++i) {
                const int m = m0 + wm + i * 16 + lm;
                const int b = m >> 10, t = m & 1023;
                ushort4 o;
                o.x = f2bf((acc[i][j][0] + bv4.x) * scl);
                o.y = f2bf((acc[i][j][1] + bv4.y) * scl);
                o.z = f2bf((acc[i][j][2] + bv4.z) * scl);
                o.w = f2bf((acc[i][j][3] + bv4.w) * scl);
                *reinterpret_cast<ushort4*>(
                    &dst[(((size_t)(b * NHEADS + h)) * SEQ + t) * DHEAD + dh0]) = o;
            }
        }
    } else {
        const int n0 = 2048 + (bx - 16) * 128;  // v rows within Bt
        FP8_KLOOP(As, Bs, A, Bt, n0, acc[i][j] = MFMA_FP8_16x16x128(af[i], bfr[j], acc[i][j]))
        const int vcol = (n0 - 2048) + wn;      // 0..1023 within v
        const int h = vcol >> 6;
        #pragma unroll
        for (int j = 0; j < 4; ++j) {
            const int dh = ((vcol & 63) + j * 16) + lm;
            const float bv = bias[2048 + vcol + j * 16 + lm];
            #pragma unroll
            for (int i = 0; i < 4; ++i) {
                const int t0 = m0 + wm + i * 16 + 4 * g;
                const int b = t0 >> 10, t = t0 & 1023;
                ushort4 o;
                o.x = f2bf(acc[i][j][0] + bv);
                o.y = f2bf(acc[i][j][1] + bv);
                o.z = f2bf(acc[i][j][2] + bv);
                o.w = f2bf(acc[i][j][3] + bv);
                *reinterpret_cast<ushort4*>(
                    &vT[(((size_t)(b * NHEADS + h)) * DHEAD + dh) * SEQ + t]) = o;
            }
        }
    }
}

// ------------------------------------------------------- Proj GEMM (fp8 MX)
// r14: same T1 swizzle; nwg=512, q=64 per XCD (8 A-panels + full 1MB B in L2).
__global__ __launch_bounds__(256, 2) void gemm_proj(
    const u8* __restrict__ A, const u8* __restrict__ Bt,
    const float* __restrict__ bias, const float* __restrict__ z,
    float* __restrict__ out)
{
    __shared__ u8 As[128 * 128];
    __shared__ u8 Bs[128 * 128];
    GEMM_PRELUDE
    const int lin = blockIdx.y * 8 + blockIdx.x;
    const int nl  = (lin & 7) * 64 + (lin >> 3);
    const int n0  = (nl & 7) * 128;
    const int m0  = (nl >> 3) * 128;
    FP8_KLOOP(As, Bs, A, Bt, n0, acc[i][j] = MFMA_FP8_16x16x128(bfr[j], af[i], acc[i][j]))
    #pragma unroll
    for (int j = 0; j < 4; ++j) {
        const int col0 = n0 + wn + j * 16 + 4 * g;
        const float4 bv4 = *reinterpret_cast<const float4*>(&bias[col0]);
        #pragma unroll
        for (int i = 0; i < 4; ++i) {
            const int m = m0 + wm + i * 16 + lm;
            const size_t idx = (size_t)m * D_MODEL + col0;
            const float4 zv = *reinterpret_cast<const float4*>(&z[idx]);
            float4 ov;
            ov.x = zv.x + acc[i][j][0] + bv4.x;
            ov.y = zv.y + acc[i][j][1] + bv4.y;
            ov.z = zv.z + acc[i][j][2] + bv4.z;
            ov.w = zv.w + acc[i][j][3] + bv4.w;
            *reinterpret_cast<float4*>(&out[idx]) = ov;
        }
    }
}

// ------------------------------------------------------------ flash attention
// r10 inner structure (proven 43us): transposed-S, fixed-max softmax, x32 PV
// via tau-permuted V, Schraudolph bf16 exp2 with offset folded into QK MFMA
// C-init, magic-add pack, MFMA-of-ones denominator, setprio; fp8 msa out.
// r18: QBLK=64 occupancy retry with the r15 failure mode removed. r15's body
// was CORRECT (passed) but __launch_bounds__(256,8) forced VGPR=32 -> total
// spill (406MB scratch writes, 205us). Loose bound (256,4) keeps the VGPR
// budget at 128; body needs ~60-80 -> 6-8 blocks/CU (LDS 17.4KB allows 9),
// vs grid-capped 4 at QBLK=128. 2x TLP on a latency-bound kernel (all pipes
// <35%). K/V staging doubles but is L2-served (bh=bi&127 XCD locality).
// (T14 reg-staging: off the table — r11 spill, r10 slow even without spill.)
#define KLD 68   // 64 + 4 pad halves (measured conflict-free r4/r6/r7)
#define EXP2_MAGIC 12582912.0f   // 1.5 * 2^23: low16(bits(x+MAGIC)) = round(x)&0xFFFF

__global__ __launch_bounds__(256, 4) void attn_kernel(
    const u16* __restrict__ Q, const u16* __restrict__ K,
    const u16* __restrict__ Vt, u8* __restrict__ msaf)
{
    __shared__ u16 Ks[64 * KLD];
    __shared__ u16 Vs[64 * KLD];
    const int tid = threadIdx.x, wave = tid >> 6, lane = tid & 63;
    const int lm = lane & 15, g = lane >> 4;
    const int bi = blockIdx.x;
    const int bh = bi & 127;            // same XCD for all q-tiles of a head
    const int q0 = (bi >> 7) * 64;
    const int b = bh >> 4, h = bh & 15;
    const size_t headBase = (size_t)bh * SEQ * DHEAD;
    const u16* Qh = Q + headBase;
    const u16* Kh = K + headBase;
    const u16* Vh = Vt + headBase;      // [64 dh][1024 t]

    const int srow = tid >> 3, sseg = tid & 7;
    const int aA = 16 * (sseg >> 2) + 4 * (sseg & 3);   // tau-permute chunk

    const uint4 onesu = {0x3F803F80u, 0x3F803F80u, 0x3F803F80u, 0x3F803F80u};
    const bf16x8 ONES = __builtin_bit_cast(bf16x8, onesu);
    // exp2 offset folded into the QK accumulator init
    const f32x4 SMINIT = {16250.0f, 16250.0f, 16250.0f, 16250.0f};

    bf16x8 qf[2];
    {
        const u16* qrow = Qh + (size_t)(q0 + wave * 16 + lm) * DHEAD;
        qf[0] = *reinterpret_cast<const bf16x8*>(qrow + g * 8);
        qf[1] = *reinterpret_cast<const bf16x8*>(qrow + 32 + g * 8);
    }

    f32x4 o[4] = {};
    f32x4 lacc = {};

    for (int j0 = 0; j0 < SEQ; j0 += 64) {
        #pragma unroll
        for (int s2 = 0; s2 < 2; ++s2) {
            const int row = srow + 32 * s2;
            *reinterpret_cast<uint4*>(&Ks[row * KLD + sseg * 8]) =
                *reinterpret_cast<const uint4*>(&Kh[(size_t)(j0 + row) * DHEAD + sseg * 8]);
            const u16* vrow = Vh + (size_t)row * SEQ + j0;
            const uint2 va = *reinterpret_cast<const uint2*>(vrow + aA);
            const uint2 vb = *reinterpret_cast<const uint2*>(vrow + 32 + aA);
            uint4 wv; wv.x = va.x; wv.y = va.y; wv.z = vb.x; wv.w = vb.y;
            *reinterpret_cast<uint4*>(&Vs[row * KLD + sseg * 8]) = wv;
        }
        __syncthreads();

        bf16x8 kf0[4], kf1[4];
        #pragma unroll
        for (int ni = 0; ni < 4; ++ni) {
            kf0[ni] = *reinterpret_cast<const bf16x8*>(&Ks[(ni*16 + lm) * KLD + g * 8]);
            kf1[ni] = *reinterpret_cast<const bf16x8*>(&Ks[(ni*16 + lm) * KLD + 32 + g * 8]);
        }

        f32x4 st[4];
        __builtin_amdgcn_s_setprio(1);
        #pragma unroll
        for (int ni = 0; ni < 4; ++ni) {
            st[ni] = __builtin_amdgcn_mfma_f32_16x16x32_bf16(kf0[ni], qf[0], SMINIT, 0, 0, 0);
            st[ni] = __builtin_amdgcn_mfma_f32_16x16x32_bf16(kf1[ni], qf[1], st[ni], 0, 0, 0);
        }
        __builtin_amdgcn_s_setprio(0);
        // magic-add: bits(st + 1.5*2^23) low16 == round(st) & 0xFFFF
        int ip[4][4];
        #pragma unroll
        for (int ni = 0; ni < 4; ++ni)
            #pragma unroll
            for (int r = 0; r < 4; ++r)
                ip[ni][r] = __builtin_bit_cast(int, st[ni][r] + EXP2_MAGIC);
        bf16x8 pfr[2];
        #pragma unroll
        for (int c = 0; c < 2; ++c) {
            uint4 u;
            u.x = pklo(ip[c][1],   ip[c][0]);
            u.y = pklo(ip[c][3],   ip[c][2]);
            u.z = pklo(ip[c+2][1], ip[c+2][0]);
            u.w = pklo(ip[c+2][3], ip[c+2][2]);
            pfr[c] = __builtin_bit_cast(bf16x8, u);
        }
        lacc = __builtin_amdgcn_mfma_f32_16x16x32_bf16(ONES, pfr[0], lacc, 0, 0, 0);
        lacc = __builtin_amdgcn_mfma_f32_16x16x32_bf16(ONES, pfr[1], lacc, 0, 0, 0);

        __builtin_amdgcn_s_setprio(1);
        #pragma unroll
        for (int mt = 0; mt < 4; ++mt) {
            bf16x8 vf0 = *reinterpret_cast<const bf16x8*>(&Vs[(mt*16 + lm) * KLD + g * 8]);
            bf16x8 vf1 = *reinterpret_cast<const bf16x8*>(&Vs[(mt*16 + lm) * KLD + 32 + g * 8]);
            o[mt] = __builtin_amdgcn_mfma_f32_16x16x32_bf16(vf0, pfr[0], o[mt], 0, 0, 0);
            o[mt] = __builtin_amdgcn_mfma_f32_16x16x32_bf16(vf1, pfr[1], o[mt], 0, 0, 0);
        }
        __builtin_amdgcn_s_setprio(0);
        __syncthreads();
    }

    {
        const float inv = 1.0f / lacc[0];
        const int t = q0 + wave * 16 + lm;
        const size_t base = ((size_t)b * SEQ + t) * D_MODEL + h * DHEAD;
        #pragma unroll
        for (int mt = 0; mt < 4; ++mt) {
            const int d0 = mt * 16 + 4 * g;
            int pk = CVT_PK_FP8(o[mt][0] * inv, o[mt][1] * inv, 0, false);
            pk = CVT_PK_FP8(o[mt][2] * inv, o[mt][3] * inv, pk, true);
            *reinterpret_cast<uint32_t*>(&msaf[base + d0]) = (uint32_t)pk;
        }
    }
}

// -------------------------------------------------------------------- launch
extern "C" void kernel_launch(void* const* d_in, const int* in_sizes, int n_in,
                              void* d_out, int out_size, void* d_ws, size_t ws_size,
                              hipStream_t stream) {
    const float* z      = (const float*)d_in[0];
    const float* ln_w   = (const float*)d_in[1];
    const float* ln_b   = (const float*)d_in[2];
    const float* W_qkv  = (const float*)d_in[3];
    const float* b_qkv  = (const float*)d_in[4];
    const float* W_proj = (const float*)d_in[5];
    const float* b_proj = (const float*)d_in[6];
    float* out = (float*)d_out;

    u8* ws = (u8*)d_ws;
    u8*  znf     = ws;                                      // fp8 [8192][1024]   8 MB
    u8*  wqkvTf  = znf + (size_t)MTOT * D_MODEL;            // fp8 [3072][1024]   3 MB
    u8*  wprojTf = wqkvTf + (size_t)3 * D_MODEL * D_MODEL;  // fp8 [1024][1024]   1 MB
    u8*  msaf    = wprojTf + (size_t)D_MODEL * D_MODEL;     // fp8 [8192][1024]   8 MB
    u16* q       = (u16*)(msaf + (size_t)MTOT * D_MODEL);   // bf16 [b,h,t,dh]   16 MB
    u16* k       = q + (size_t)MTOT * D_MODEL;              // bf16 [b,h,t,dh]   16 MB
    u16* vT      = k + (size_t)MTOT * D_MODEL;              // bf16 [b,h,dh,t]   16 MB

    prep_inputs<<<MTOT + 4096, 256, 0, stream>>>(
        z, ln_w, ln_b, (uint32_t*)znf, W_qkv, W_proj, wqkvTf, wprojTf);
    gemm_qkv<<<dim3(24, MTOT / 128), 256, 0, stream>>>(znf, wqkvTf, b_qkv, q, k, vT);
    attn_kernel<<<BATCH * NHEADS * (SEQ / 64), 256, 0, stream>>>(q, k, vT, msaf);
    gemm_proj<<<dim3(D_MODEL / 128, MTOT / 128), 256, 0, stream>>>(
        msaf, wprojTf, b_proj, z, out);
}

// Round 13
// 198.677 us; speedup vs baseline: 1.8091x; 1.0835x over previous
//
#include <hip/hip_runtime.h>
#include <stdint.h>

typedef unsigned short u16;
typedef uint8_t u8;
typedef __bf16 bf16x8 __attribute__((ext_vector_type(8)));
typedef float f32x4 __attribute__((ext_vector_type(4)));
typedef int i32x8 __attribute__((ext_vector_type(8)));

#define D_MODEL 1024
#define NHEADS  16
#define DHEAD   64
#define BATCH   8
#define SEQ     1024
#define MTOT    (BATCH*SEQ)          // 8192 rows

#define GPTR(p) ((const __attribute__((address_space(1))) void*)(p))
#define LPTR(p) ((__attribute__((address_space(3))) void*)(p))

// Device-only builtins (host pass just needs to parse — r2 lesson)
#if defined(__HIP_DEVICE_COMPILE__)
  #define MFMA_FP8_16x16x128(a, b, c) \
      __builtin_amdgcn_mfma_scale_f32_16x16x128_f8f6f4((a), (b), (c), 0, 0, 0, 127, 0, 127)
  #define CVT_PK_FP8(a, b, old, w) __builtin_amdgcn_cvt_pk_fp8_f32((a), (b), (old), (w))
#else
  #define MFMA_FP8_16x16x128(a, b, c) (c)
  #define CVT_PK_FP8(a, b, old, w) (0)
#endif

__device__ __forceinline__ u16 f2bf(float f) {
    union { float f; uint32_t u; } v; v.f = f;
    uint32_t u = v.u;
    u += 0x7fffu + ((u >> 16) & 1u);  // RNE
    return (u16)(u >> 16);
}

// pack low16 of two ints: result = [i1.low16 : i0.low16]
__device__ __forceinline__ uint32_t pklo(int i1, int i0) {
    return __builtin_amdgcn_perm((uint32_t)i1, (uint32_t)i0, 0x05040100u);
}

// --------------- merged prep: LayerNorm->fp8 (blocks 0..8191) and
//                 weight transpose->fp8 (blocks 8192..12287)
__global__ __launch_bounds__(256) void prep_inputs(
    const float* __restrict__ z, const float* __restrict__ w,
    const float* __restrict__ b, uint32_t* __restrict__ znf,
    const float* __restrict__ Wqkv, const float* __restrict__ Wproj,
    u8* __restrict__ outQkv, u8* __restrict__ outProj)
{
    __shared__ float red[8];
    __shared__ u8 tile[32][36];
    const int bid = blockIdx.x;
    const int t = threadIdx.x;
    if (bid < MTOT) {
        // ---- LayerNorm row
        const int row = bid;
        const float4 v = reinterpret_cast<const float4*>(z + (size_t)row * D_MODEL)[t];
        float s  = v.x + v.y + v.z + v.w;
        float s2 = v.x*v.x + v.y*v.y + v.z*v.z + v.w*v.w;
        #pragma unroll
        for (int off = 32; off; off >>= 1) {
            s  += __shfl_down(s,  off, 64);
            s2 += __shfl_down(s2, off, 64);
        }
        const int wave = t >> 6, lane = t & 63;
        if (lane == 0) { red[wave] = s; red[wave + 4] = s2; }
        __syncthreads();
        if (t == 0) {
            float ts  = red[0] + red[1] + red[2] + red[3];
            float ts2 = red[4] + red[5] + red[6] + red[7];
            float mu  = ts * (1.0f / D_MODEL);
            float var = ts2 * (1.0f / D_MODEL) - mu * mu;
            red[0] = mu; red[1] = rsqrtf(var + 1e-5f);
        }
        __syncthreads();
        const float mu = red[0], rstd = red[1];
        const float4 wv = reinterpret_cast<const float4*>(w)[t];
        const float4 bv = reinterpret_cast<const float4*>(b)[t];
        const float x0 = (v.x - mu) * rstd * wv.x + bv.x;
        const float x1 = (v.y - mu) * rstd * wv.y + bv.y;
        const float x2 = (v.z - mu) * rstd * wv.z + bv.z;
        const float x3 = (v.w - mu) * rstd * wv.w + bv.w;
        int pk = CVT_PK_FP8(x0, x1, 0, false);
        pk = CVT_PK_FP8(x2, x3, pk, true);
        znf[(size_t)row * (D_MODEL / 4) + t] = (uint32_t)pk;
    } else {
        // ---- weight transpose + fp8 cast (32x32 tile)
        const int bx = bid - MTOT;            // 0..4095
        const int cx = bx & 127;              // 128 column-tiles
        const int r0 = (bx >> 7) * 32;        // 32 row-tiles
        const float* in; u8* out; int C;
        if (cx < 96) { in = Wqkv;  out = outQkv;  C = 3072; }
        else         { in = Wproj; out = outProj; C = 1024; }
        const int c0 = (cx < 96 ? cx : cx - 96) * 32;
        const int tx = t & 31, ty = t >> 5;   // 32x8
        #pragma unroll
        for (int i = 0; i < 4; ++i) {
            const float f = in[(size_t)(r0 + ty + i*8) * C + c0 + tx];
            tile[ty + i*8][tx] = (u8)(CVT_PK_FP8(f, 0.f, 0, false) & 0xFF);
        }
        __syncthreads();
        #pragma unroll
        for (int i = 0; i < 4; ++i)
            out[(size_t)(c0 + ty + i*8) * D_MODEL + r0 + tx] = tile[tx][ty + i*8];
    }
}

// q scale: 0.125 * log2(e) * 128 — the x128 of the Schraudolph exp2 is folded
// into the q values themselves; the +16250 offset is folded into the QK MFMA
// C-operand (SMINIT in attn_kernel). So the per-score softmax work is a single
// magic-add (v_add_f32) + perm pack.
#define QSCALE 23.0831207f

// ---------------------------------------------------------- fp8 GEMM mainloop
// r10 single-buffer form (proven): 128x128 tile, K-tile=128B, 4 waves;
// XOR swizzle; global_load_lds width-16. (2-phase dbuf tested r4: neutral,
// matches the m99/m100 known-null; costs LDS.)
#define GEMM_PRELUDE                                                            \
    const int tid = threadIdx.x;                                                \
    const int wave = tid >> 6, lane = tid & 63;                                 \
    const int lm = lane & 15, g = lane >> 4;                                    \
    const int wm = (wave >> 1) * 64, wn = (wave & 1) * 64;                      \
    const int srow = tid >> 3;                                                  \
    const int sseg = tid & 7;                                                   \
    const int sgcol = (sseg ^ (srow & 7)) * 16;                                 \
    const int xl = lm & 7;                                                      \
    const int ca0 = ((2 * g) ^ xl) * 16;                                        \
    const int ca1 = ((2 * g + 1) ^ xl) * 16;

#define FP8_KLOOP(As_, Bs_, A_, Bt_, n0_, MFMA_STMT)                            \
    f32x4 acc[4][4] = {};                                                       \
    for (int k0 = 0; k0 < D_MODEL; k0 += 128) {                                 \
        _Pragma("unroll")                                                       \
        for (int c = 0; c < 4; ++c) {                                           \
            const int r = srow + c * 32;                                        \
            __builtin_amdgcn_global_load_lds(                                   \
                GPTR(&A_[(size_t)(m0 + r) * D_MODEL + k0 + sgcol]),             \
                LPTR(&As_[r * 128 + sseg * 16]), 16, 0, 0);                     \
            __builtin_amdgcn_global_load_lds(                                   \
                GPTR(&Bt_[(size_t)((n0_) + r) * D_MODEL + k0 + sgcol]),         \
                LPTR(&Bs_[r * 128 + sseg * 16]), 16, 0, 0);                     \
        }                                                                       \
        __syncthreads();                                                        \
        i32x8 af[4], bfr[4];                                                    \
        _Pragma("unroll")                                                       \
        for (int i = 0; i < 4; ++i) {                                           \
            const uint4 alo = *reinterpret_cast<const uint4*>(&As_[(wm + i*16 + lm) * 128 + ca0]); \
            const uint4 ahi = *reinterpret_cast<const uint4*>(&As_[(wm + i*16 + lm) * 128 + ca1]); \
            af[i][0] = alo.x; af[i][1] = alo.y; af[i][2] = alo.z; af[i][3] = alo.w; \
            af[i][4] = ahi.x; af[i][5] = ahi.y; af[i][6] = ahi.z; af[i][7] = ahi.w; \
            const uint4 blo = *reinterpret_cast<const uint4*>(&Bs_[(wn + i*16 + lm) * 128 + ca0]); \
            const uint4 bhi = *reinterpret_cast<const uint4*>(&Bs_[(wn + i*16 + lm) * 128 + ca1]); \
            bfr[i][0] = blo.x; bfr[i][1] = blo.y; bfr[i][2] = blo.z; bfr[i][3] = blo.w; \
            bfr[i][4] = bhi.x; bfr[i][5] = bhi.y; bfr[i][6] = bhi.z; bfr[i][7] = bhi.w; \
        }                                                                       \
        _Pragma("unroll")                                                       \
        for (int i = 0; i < 4; ++i)                                             \
            _Pragma("unroll")                                                   \
            for (int j = 0; j < 4; ++j)                                         \
                MFMA_STMT;                                                      \
        __syncthreads();                                                        \
    }

// -------------------------------------------- merged QKV GEMM (r13/r14)
// grid x: 0..15 = q/k columns (swapped-operand MFMA, lane owns 4 dh);
//         16..23 = v columns (unswapped, writes vT[b,h,dh,t] direct).
// r14: T1 XCD-aware bijective swizzle — each XCD gets 192 consecutive tiles
// (8 A-panels x full B sweep ~= 4MB = its L2). nwg=1536 %8==0 -> valid.
__global__ __launch_bounds__(256, 2) void gemm_qkv(
    const u8* __restrict__ A, const u8* __restrict__ Bt,
    const float* __restrict__ bias,
    u16* __restrict__ q, u16* __restrict__ k, u16* __restrict__ vT)
{
    __shared__ u8 As[128 * 128];
    __shared__ u8 Bs[128 * 128];
    GEMM_PRELUDE
    const int lin = blockIdx.y * 24 + blockIdx.x;   // HW dispatch order (x fastest)
    const int nl  = (lin & 7) * 192 + (lin >> 3);   // XCD-contiguous remap
    const int bx  = nl % 24;
    const int m0  = (nl / 24) * 128;
    if (bx < 16) {
        const int n0 = bx * 128;
        FP8_KLOOP(As, Bs, A, Bt, n0, acc[i][j] = MFMA_FP8_16x16x128(bfr[j], af[i], acc[i][j]))
        const int colbase = n0 + wn;
        const int sel = colbase >> 10;          // 0=q 1=k
        const int h = (colbase & 1023) >> 6;
        u16* dst = (sel == 0) ? q : k;
        const float scl = (sel == 0) ? QSCALE : 1.0f;
        #pragma unroll
        for (int j = 0; j < 4; ++j) {
            const int dh0 = j * 16 + 4 * g;
            const float4 bv4 = *reinterpret_cast<const float4*>(&bias[colbase + dh0]);
            #pragma unroll
            for (int i = 0; i < 4; ++i) {
                const int m = m0 + wm + i * 16 + lm;
                const int b = m >> 10, t = m & 1023;
                ushort4 o;
                o.x = f2bf((acc[i][j][0] + bv4.x) * scl);
                o.y = f2bf((acc[i][j][1] + bv4.y) * scl);
                o.z = f2bf((acc[i][j][2] + bv4.z) * scl);
                o.w = f2bf((acc[i][j][3] + bv4.w) * scl);
                *reinterpret_cast<ushort4*>(
                    &dst[(((size_t)(b * NHEADS + h)) * SEQ + t) * DHEAD + dh0]) = o;
            }
        }
    } else {
        const int n0 = 2048 + (bx - 16) * 128;  // v rows within Bt
        FP8_KLOOP(As, Bs, A, Bt, n0, acc[i][j] = MFMA_FP8_16x16x128(af[i], bfr[j], acc[i][j]))
        const int vcol = (n0 - 2048) + wn;      // 0..1023 within v
        const int h = vcol >> 6;
        #pragma unroll
        for (int j = 0; j < 4; ++j) {
            const int dh = ((vcol & 63) + j * 16) + lm;
            const float bv = bias[2048 + vcol + j * 16 + lm];
            #pragma unroll
            for (int i = 0; i < 4; ++i) {
                const int t0 = m0 + wm + i * 16 + 4 * g;
                const int b = t0 >> 10, t = t0 & 1023;
                ushort4 o;
                o.x = f2bf(acc[i][j][0] + bv);
                o.y = f2bf(acc[i][j][1] + bv);
                o.z = f2bf(acc[i][j][2] + bv);
                o.w = f2bf(acc[i][j][3] + bv);
                *reinterpret_cast<ushort4*>(
                    &vT[(((size_t)(b * NHEADS + h)) * DHEAD + dh) * SEQ + t]) = o;
            }
        }
    }
}

// ------------------------------------------------------- Proj GEMM (fp8 MX)
// r14: same T1 swizzle; nwg=512, q=64 per XCD (8 A-panels + full 1MB B in L2).
__global__ __launch_bounds__(256, 2) void gemm_proj(
    const u8* __restrict__ A, const u8* __restrict__ Bt,
    const float* __restrict__ bias, const float* __restrict__ z,
    float* __restrict__ out)
{
    __shared__ u8 As[128 * 128];
    __shared__ u8 Bs[128 * 128];
    GEMM_PRELUDE
    const int lin = blockIdx.y * 8 + blockIdx.x;
    const int nl  = (lin & 7) * 64 + (lin >> 3);
    const int n0  = (nl & 7) * 128;
    const int m0  = (nl >> 3) * 128;
    FP8_KLOOP(As, Bs, A, Bt, n0, acc[i][j] = MFMA_FP8_16x16x128(bfr[j], af[i], acc[i][j]))
    #pragma unroll
    for (int j = 0; j < 4; ++j) {
        const int col0 = n0 + wn + j * 16 + 4 * g;
        const float4 bv4 = *reinterpret_cast<const float4*>(&bias[col0]);
        #pragma unroll
        for (int i = 0; i < 4; ++i) {
            const int m = m0 + wm + i * 16 + lm;
            const size_t idx = (size_t)m * D_MODEL + col0;
            const float4 zv = *reinterpret_cast<const float4*>(&z[idx]);
            float4 ov;
            ov.x = zv.x + acc[i][j][0] + bv4.x;
            ov.y = zv.y + acc[i][j][1] + bv4.y;
            ov.z = zv.z + acc[i][j][2] + bv4.z;
            ov.w = zv.w + acc[i][j][3] + bv4.w;
            *reinterpret_cast<float4*>(&out[idx]) = ov;
        }
    }
}

// ------------------------------------------------------------ flash attention
// r10 form EXACTLY (proven 43us; best of 7 attn variants tried r10-r18):
// transposed-S, fixed-max softmax, 128 q-rows/block, x32 PV via tau-permuted
// V, Schraudolph bf16 exp2 with offset folded into QK MFMA C-init, magic-add
// pack, MFMA-of-ones denominator, setprio around MFMA clusters; fp8 msa out.
// FAILED variants (do not retry): r11/r16 T14 reg-staging (spill at (256,4);
// slow even unspilled at (256,2): 68us, FETCH +50%); r13 KVBLK=128 dbl-stage
// (48us); r15 QBLK=64 tight bounds (VGPR32 spill, 205us); r18 QBLK=64 loose
// bounds (59.8us — occupancy 40% but arithmetic intensity halved, FETCH
// 30->54MB, MfmaUtil 34->26). Latency-bound local optimum at 43us.
#define KLD 68   // 64 + 4 pad halves (measured conflict-free r4/r6/r7)
#define EXP2_MAGIC 12582912.0f   // 1.5 * 2^23: low16(bits(x+MAGIC)) = round(x)&0xFFFF

__global__ __launch_bounds__(256, 4) void attn_kernel(
    const u16* __restrict__ Q, const u16* __restrict__ K,
    const u16* __restrict__ Vt, u8* __restrict__ msaf)
{
    __shared__ u16 Ks[64 * KLD];
    __shared__ u16 Vs[64 * KLD];
    const int tid = threadIdx.x, wave = tid >> 6, lane = tid & 63;
    const int lm = lane & 15, g = lane >> 4;
    const int bi = blockIdx.x;
    const int bh = bi & 127;            // same XCD for all q-tiles of a head
    const int q0 = (bi >> 7) * 128;
    const int b = bh >> 4, h = bh & 15;
    const size_t headBase = (size_t)bh * SEQ * DHEAD;
    const u16* Qh = Q + headBase;
    const u16* Kh = K + headBase;
    const u16* Vh = Vt + headBase;      // [64 dh][1024 t]

    const int srow = tid >> 3, sseg = tid & 7;
    const int aA = 16 * (sseg >> 2) + 4 * (sseg & 3);   // tau-permute chunk

    const uint4 onesu = {0x3F803F80u, 0x3F803F80u, 0x3F803F80u, 0x3F803F80u};
    const bf16x8 ONES = __builtin_bit_cast(bf16x8, onesu);
    // exp2 offset folded into the QK accumulator init
    const f32x4 SMINIT = {16250.0f, 16250.0f, 16250.0f, 16250.0f};

    bf16x8 qf[2][2];
    #pragma unroll
    for (int s = 0; s < 2; ++s) {
        const u16* qrow = Qh + (size_t)(q0 + s * 64 + wave * 16 + lm) * DHEAD;
        qf[s][0] = *reinterpret_cast<const bf16x8*>(qrow + g * 8);
        qf[s][1] = *reinterpret_cast<const bf16x8*>(qrow + 32 + g * 8);
    }

    f32x4 o[2][4] = {};
    f32x4 lacc[2] = {};

    for (int j0 = 0; j0 < SEQ; j0 += 64) {
        #pragma unroll
        for (int s2 = 0; s2 < 2; ++s2) {
            const int row = srow + 32 * s2;
            *reinterpret_cast<uint4*>(&Ks[row * KLD + sseg * 8]) =
                *reinterpret_cast<const uint4*>(&Kh[(size_t)(j0 + row) * DHEAD + sseg * 8]);
            const u16* vrow = Vh + (size_t)row * SEQ + j0;
            const uint2 va = *reinterpret_cast<const uint2*>(vrow + aA);
            const uint2 vb = *reinterpret_cast<const uint2*>(vrow + 32 + aA);
            uint4 wv; wv.x = va.x; wv.y = va.y; wv.z = vb.x; wv.w = vb.y;
            *reinterpret_cast<uint4*>(&Vs[row * KLD + sseg * 8]) = wv;
        }
        __syncthreads();

        bf16x8 kf0[4], kf1[4];
        #pragma unroll
        for (int ni = 0; ni < 4; ++ni) {
            kf0[ni] = *reinterpret_cast<const bf16x8*>(&Ks[(ni*16 + lm) * KLD + g * 8]);
            kf1[ni] = *reinterpret_cast<const bf16x8*>(&Ks[(ni*16 + lm) * KLD + 32 + g * 8]);
        }

        bf16x8 pfr[2][2];
        #pragma unroll
        for (int s = 0; s < 2; ++s) {
            f32x4 st[4];
            __builtin_amdgcn_s_setprio(1);
            #pragma unroll
            for (int ni = 0; ni < 4; ++ni) {
                st[ni] = __builtin_amdgcn_mfma_f32_16x16x32_bf16(kf0[ni], qf[s][0], SMINIT, 0, 0, 0);
                st[ni] = __builtin_amdgcn_mfma_f32_16x16x32_bf16(kf1[ni], qf[s][1], st[ni], 0, 0, 0);
            }
            __builtin_amdgcn_s_setprio(0);
            // magic-add: bits(st + 1.5*2^23) low16 == round(st) & 0xFFFF
            int ip[4][4];
            #pragma unroll
            for (int ni = 0; ni < 4; ++ni)
                #pragma unroll
                for (int r = 0; r < 4; ++r)
                    ip[ni][r] = __builtin_bit_cast(int, st[ni][r] + EXP2_MAGIC);
            #pragma unroll
            for (int c = 0; c < 2; ++c) {
                uint4 u;
                u.x = pklo(ip[c][1],   ip[c][0]);
                u.y = pklo(ip[c][3],   ip[c][2]);
                u.z = pklo(ip[c+2][1], ip[c+2][0]);
                u.w = pklo(ip[c+2][3], ip[c+2][2]);
                pfr[s][c] = __builtin_bit_cast(bf16x8, u);
            }
            lacc[s] = __builtin_amdgcn_mfma_f32_16x16x32_bf16(ONES, pfr[s][0], lacc[s], 0, 0, 0);
            lacc[s] = __builtin_amdgcn_mfma_f32_16x16x32_bf16(ONES, pfr[s][1], lacc[s], 0, 0, 0);
        }

        __builtin_amdgcn_s_setprio(1);
        #pragma unroll
        for (int mt = 0; mt < 4; ++mt) {
            bf16x8 vf0 = *reinterpret_cast<const bf16x8*>(&Vs[(mt*16 + lm) * KLD + g * 8]);
            bf16x8 vf1 = *reinterpret_cast<const bf16x8*>(&Vs[(mt*16 + lm) * KLD + 32 + g * 8]);
            #pragma unroll
            for (int s = 0; s < 2; ++s) {
                o[s][mt] = __builtin_amdgcn_mfma_f32_16x16x32_bf16(vf0, pfr[s][0], o[s][mt], 0, 0, 0);
                o[s][mt] = __builtin_amdgcn_mfma_f32_16x16x32_bf16(vf1, pfr[s][1], o[s][mt], 0, 0, 0);
            }
        }
        __builtin_amdgcn_s_setprio(0);
        __syncthreads();
    }

    #pragma unroll
    for (int s = 0; s < 2; ++s) {
        const float inv = 1.0f / lacc[s][0];
        const int t = q0 + s * 64 + wave * 16 + lm;
        const size_t base = ((size_t)b * SEQ + t) * D_MODEL + h * DHEAD;
        #pragma unroll
        for (int mt = 0; mt < 4; ++mt) {
            const int d0 = mt * 16 + 4 * g;
            int pk = CVT_PK_FP8(o[s][mt][0] * inv, o[s][mt][1] * inv, 0, false);
            pk = CVT_PK_FP8(o[s][mt][2] * inv, o[s][mt][3] * inv, pk, true);
            *reinterpret_cast<uint32_t*>(&msaf[base + d0]) = (uint32_t)pk;
        }
    }
}

// -------------------------------------------------------------------- launch
extern "C" void kernel_launch(void* const* d_in, const int* in_sizes, int n_in,
                              void* d_out, int out_size, void* d_ws, size_t ws_size,
                              hipStream_t stream) {
    const float* z      = (const float*)d_in[0];
    const float* ln_w   = (const float*)d_in[1];
    const float* ln_b   = (const float*)d_in[2];
    const float* W_qkv  = (const float*)d_in[3];
    const float* b_qkv  = (const float*)d_in[4];
    const float* W_proj = (const float*)d_in[5];
    const float* b_proj = (const float*)d_in[6];
    float* out = (float*)d_out;

    u8* ws = (u8*)d_ws;
    u8*  znf     = ws;                                      // fp8 [8192][1024]   8 MB
    u8*  wqkvTf  = znf + (size_t)MTOT * D_MODEL;            // fp8 [3072][1024]   3 MB
    u8*  wprojTf = wqkvTf + (size_t)3 * D_MODEL * D_MODEL;  // fp8 [1024][1024]   1 MB
    u8*  msaf    = wprojTf + (size_t)D_MODEL * D_MODEL;     // fp8 [8192][1024]   8 MB
    u16* q       = (u16*)(msaf + (size_t)MTOT * D_MODEL);   // bf16 [b,h,t,dh]   16 MB
    u16* k       = q + (size_t)MTOT * D_MODEL;              // bf16 [b,h,t,dh]   16 MB
    u16* vT      = k + (size_t)MTOT * D_MODEL;              // bf16 [b,h,dh,t]   16 MB

    prep_inputs<<<MTOT + 4096, 256, 0, stream>>>(
        z, ln_w, ln_b, (uint32_t*)znf, W_qkv, W_proj, wqkvTf, wprojTf);
    gemm_qkv<<<dim3(24, MTOT / 128), 256, 0, stream>>>(znf, wqkvTf, b_qkv, q, k, vT);
    attn_kernel<<<BATCH * NHEADS * (SEQ / 128), 256, 0, stream>>>(q, k, vT, msaf);
    gemm_proj<<<dim3(D_MODEL / 128, MTOT / 128), 256, 0, stream>>>(
        msaf, wprojTf, b_proj, z, out);
}